// Round 12
// baseline (931.537 us; speedup 1.0000x reference)
//
#include <hip/hip_runtime.h>
#include <cstdint>

typedef unsigned short u16;
typedef unsigned int u32;
typedef __attribute__((ext_vector_type(8))) short bf16x8;
typedef __attribute__((ext_vector_type(8))) unsigned short u16x8;
typedef __attribute__((ext_vector_type(4))) float f32x4;

struct us4 { u16 a, b, c, d; };

__device__ __forceinline__ u16 f2bf(float f) {
    uint32_t u = __float_as_uint(f);
    uint32_t r = (u + 0x7FFFu + ((u >> 16) & 1u)) >> 16;
    return (u16)r;
}
__device__ __forceinline__ float bf2f(u16 h) { return __uint_as_float(((uint32_t)h) << 16); }
__device__ __forceinline__ float sigm(float x) { return 1.f / (1.f + expf(-x)); }
__device__ __forceinline__ float dot4(float4 a, float4 b) {
    return a.x * b.x + a.y * b.y + a.z * b.z + a.w * b.w;
}
__device__ __forceinline__ float wave_sum(float v) {
#pragma unroll
    for (int o = 32; o; o >>= 1) v += __shfl_down(v, o);
    return v;
}
__device__ __forceinline__ float wave_max(float v) {
#pragma unroll
    for (int o = 32; o; o >>= 1) v = fmaxf(v, __shfl_down(v, o));
    return v;
}

// Coherent (device-scope, relaxed) u32 access: no cache maintenance.
__device__ __forceinline__ void ast(u32* p, u32 v) {
    __hip_atomic_store(p, v, __ATOMIC_RELAXED, __HIP_MEMORY_SCOPE_AGENT);
}
__device__ __forceinline__ u32 ald(const u32* p) {
    return __hip_atomic_load(p, __ATOMIC_RELAXED, __HIP_MEMORY_SCOPE_AGENT);
}
__device__ __forceinline__ u32 packsplit(float v) {
    u16 h = f2bf(v);
    u16 l = f2bf(v - bf2f(h));
    return (u32)h | ((u32)l << 16);
}

// Flag barrier: one own-cacheline flag per block, parallel poll.
template <int NBLK>
__device__ __forceinline__ void fbar(u32* flags, int me, u32 gen) {
    asm volatile("s_waitcnt vmcnt(0)" ::: "memory");
    __syncthreads();
    if (threadIdx.x == 0) ast(&flags[me * 32], gen);
    if (threadIdx.x < NBLK) {
        while (ald(&flags[threadIdx.x * 32]) < gen)
            __builtin_amdgcn_s_sleep(1);
    }
    __syncthreads();
    asm volatile("" ::: "memory");
}

// ---------------------------------------------------------------------------
// Generic 128x128-tile BT GEMM (register-staged) — mid-size GEMMs.
// ---------------------------------------------------------------------------
template <bool SPLIT, int AMODE, int EPI, int XMAJ = 0>
__global__ __launch_bounds__(256) void gemm_bt(
    const u16* __restrict__ AH, const u16* __restrict__ AL, int lda, long strideA,
    const u16* __restrict__ BH, const u16* __restrict__ BL, int ldb, long strideB,
    float* __restrict__ C, u16* __restrict__ CH, u16* __restrict__ CL,
    int ldc, long strideC, const float* __restrict__ bias, int K)
{
    constexpr int TL = 40;
    constexpr int CHK = 128 * TL;
    __shared__ u16 sm[(SPLIT ? 4 : 2) * CHK];
    u16* sAH = sm;
    u16* sBH = sm + CHK;
    u16* sAL = SPLIT ? sm + 2 * CHK : sm;
    u16* sBL = SPLIT ? sm + 3 * CHK : sm;

    const int tid = threadIdx.x;
    const int lane = tid & 63, w = tid >> 6;
    const int wm = w >> 1, wn = w & 1;
    const int lane15 = lane & 15, q8 = (lane >> 4) << 3;
    const int n0 = (XMAJ ? blockIdx.y : blockIdx.x) * 128;
    const int m0 = (XMAJ ? blockIdx.x : blockIdx.y) * 128;
    const int z = blockIdx.z;

    const int r = tid >> 2, c8 = (tid & 3) * 8;

    long aoff[2], boff[2];
#pragma unroll
    for (int h2 = 0; h2 < 2; ++h2) {
        int row = r + (h2 << 6);
        if (AMODE == 0) {
            aoff[h2] = strideA * z + (long)(m0 + row) * lda + c8;
        } else {
            int m = m0 + row;
            int t = m % 40, dd = m / 40;
            aoff[h2] = ((long)(t + 1) * 128 + (z * 16 + dd)) * 512 + c8;
        }
        boff[h2] = strideB * z + (long)(n0 + row) * ldb + c8;
    }

    f32x4 acc[4][4] = {};

    for (int k0 = 0; k0 < K; k0 += 32) {
#pragma unroll
        for (int h2 = 0; h2 < 2; ++h2) {
            int row = r + (h2 << 6);
            int sidx = row * TL + c8;
            *(u16x8*)&sAH[sidx] = *(const u16x8*)&AH[aoff[h2] + k0];
            *(u16x8*)&sBH[sidx] = *(const u16x8*)&BH[boff[h2] + k0];
            if constexpr (SPLIT) {
                *(u16x8*)&sAL[sidx] = *(const u16x8*)&AL[aoff[h2] + k0];
                *(u16x8*)&sBL[sidx] = *(const u16x8*)&BL[boff[h2] + k0];
            }
        }
        __syncthreads();

        bf16x8 a[4], b[4], al[4], bl[4];
#pragma unroll
        for (int i = 0; i < 4; ++i) {
            a[i] = *(const bf16x8*)&sAH[(wm * 64 + i * 16 + lane15) * TL + q8];
            b[i] = *(const bf16x8*)&sBH[(wn * 64 + i * 16 + lane15) * TL + q8];
            if constexpr (SPLIT) {
                al[i] = *(const bf16x8*)&sAL[(wm * 64 + i * 16 + lane15) * TL + q8];
                bl[i] = *(const bf16x8*)&sBL[(wn * 64 + i * 16 + lane15) * TL + q8];
            }
        }
#pragma unroll
        for (int mt = 0; mt < 4; ++mt)
#pragma unroll
            for (int nt = 0; nt < 4; ++nt) {
                acc[mt][nt] = __builtin_amdgcn_mfma_f32_16x16x32_bf16(a[mt], b[nt], acc[mt][nt], 0, 0, 0);
                if constexpr (SPLIT) {
                    acc[mt][nt] = __builtin_amdgcn_mfma_f32_16x16x32_bf16(a[mt], bl[nt], acc[mt][nt], 0, 0, 0);
                    acc[mt][nt] = __builtin_amdgcn_mfma_f32_16x16x32_bf16(al[mt], b[nt], acc[mt][nt], 0, 0, 0);
                }
            }
        __syncthreads();
    }

#pragma unroll
    for (int mt = 0; mt < 4; ++mt)
#pragma unroll
        for (int nt = 0; nt < 4; ++nt)
#pragma unroll
            for (int i = 0; i < 4; ++i) {
                int row = m0 + wm * 64 + mt * 16 + ((lane >> 4) << 2) + i;
                int col = n0 + wn * 64 + nt * 16 + lane15;
                long off = strideC * z + (long)row * ldc + col;
                float v = acc[mt][nt][i];
                if constexpr (EPI == 0) {
                    C[off] = v;
                } else if constexpr (EPI == 1) {
                    C[off] = v + bias[col];
                } else if constexpr (EPI == 2) {
                    u16 h_ = f2bf(v);
                    CH[off] = h_;
                    CL[off] = f2bf(v - bf2f(h_));
                } else if constexpr (EPI == 3) {
                    CH[off] = f2bf(tanhf(v));
                } else {
                    CH[off] = f2bf(v);
                }
            }
}

// ---------------------------------------------------------------------------
// Head GEMM body (shared by standalone kernel + merged doc kernel).
// bid mapping: 0-99 sq1; 100-199 E0q; 200-299 E0o; 300-939 xW.
// ---------------------------------------------------------------------------
__device__ __forceinline__ void run_head_gemm(
    int bid, u16* __restrict__ smem,
    const u16* __restrict__ enc1H, const u16* __restrict__ enc1L,
    const u16* __restrict__ wqTH,  const u16* __restrict__ wqTL,
    const u16* __restrict__ enc0H, const u16* __restrict__ enc0L,
    const u16* __restrict__ wqdTH, const u16* __restrict__ wqdTL,
    const u16* __restrict__ woCH,  const u16* __restrict__ woCL,
    const u16* __restrict__ xinH,  const u16* __restrict__ xinL,
    const u16* __restrict__ WihH,  const u16* __restrict__ WihL,
    u16* __restrict__ sq1H, u16* __restrict__ sq1L,
    float* __restrict__ E0q, float* __restrict__ E0o,
    float* __restrict__ xW, const float* __restrict__ biasc)
{
    constexpr int TL = 40;
    constexpr int CHK = 128 * TL;
    u16* sAH = smem;
    u16* sBH = smem + CHK;
    u16* sAL = smem + 2 * CHK;
    u16* sBL = smem + 3 * CHK;

    const u16 *AH, *AL, *BH, *BL;
    int task, n0, m0, ldc;
    if (bid < 300) {
        task = bid / 100;
        int rr = bid % 100;
        n0 = (rr & 3) * 128; m0 = (rr >> 2) * 128; ldc = 512;
        if (task == 0)      { AH = enc1H; AL = enc1L; BH = wqTH;  BL = wqTL;  }
        else if (task == 1) { AH = enc0H; AL = enc0L; BH = wqdTH; BL = wqdTL; }
        else                { AH = enc0H; AL = enc0L; BH = woCH;  BL = woCL;  }
    } else {
        task = 3;
        int rr = bid - 300;
        n0 = (rr & 15) * 128; m0 = (rr >> 4) * 128; ldc = 2048;
        AH = xinH; AL = xinL; BH = WihH; BL = WihL;
    }

    const int tid = threadIdx.x;
    const int lane = tid & 63, w = tid >> 6;
    const int wm = w >> 1, wn = w & 1;
    const int lane15 = lane & 15, q8 = (lane >> 4) << 3;
    const int r = tid >> 2, c8 = (tid & 3) * 8;

    long aoff[2], boff[2];
#pragma unroll
    for (int h2 = 0; h2 < 2; ++h2) {
        int row = r + (h2 << 6);
        aoff[h2] = (long)(m0 + row) * 512 + c8;
        boff[h2] = (long)(n0 + row) * 512 + c8;
    }

    f32x4 acc[4][4] = {};
    for (int k0 = 0; k0 < 512; k0 += 32) {
#pragma unroll
        for (int h2 = 0; h2 < 2; ++h2) {
            int row = r + (h2 << 6);
            int sidx = row * TL + c8;
            *(u16x8*)&sAH[sidx] = *(const u16x8*)&AH[aoff[h2] + k0];
            *(u16x8*)&sBH[sidx] = *(const u16x8*)&BH[boff[h2] + k0];
            *(u16x8*)&sAL[sidx] = *(const u16x8*)&AL[aoff[h2] + k0];
            *(u16x8*)&sBL[sidx] = *(const u16x8*)&BL[boff[h2] + k0];
        }
        __syncthreads();
        bf16x8 a[4], b[4], al[4], bl[4];
#pragma unroll
        for (int i = 0; i < 4; ++i) {
            a[i]  = *(const bf16x8*)&sAH[(wm * 64 + i * 16 + lane15) * TL + q8];
            b[i]  = *(const bf16x8*)&sBH[(wn * 64 + i * 16 + lane15) * TL + q8];
            al[i] = *(const bf16x8*)&sAL[(wm * 64 + i * 16 + lane15) * TL + q8];
            bl[i] = *(const bf16x8*)&sBL[(wn * 64 + i * 16 + lane15) * TL + q8];
        }
#pragma unroll
        for (int mt = 0; mt < 4; ++mt)
#pragma unroll
            for (int nt = 0; nt < 4; ++nt) {
                acc[mt][nt] = __builtin_amdgcn_mfma_f32_16x16x32_bf16(a[mt],  b[nt],  acc[mt][nt], 0, 0, 0);
                acc[mt][nt] = __builtin_amdgcn_mfma_f32_16x16x32_bf16(a[mt],  bl[nt], acc[mt][nt], 0, 0, 0);
                acc[mt][nt] = __builtin_amdgcn_mfma_f32_16x16x32_bf16(al[mt], b[nt],  acc[mt][nt], 0, 0, 0);
            }
        __syncthreads();
    }

#pragma unroll
    for (int mt = 0; mt < 4; ++mt)
#pragma unroll
        for (int nt = 0; nt < 4; ++nt)
#pragma unroll
            for (int i = 0; i < 4; ++i) {
                int row = m0 + wm * 64 + mt * 16 + ((lane >> 4) << 2) + i;
                int col = n0 + wn * 64 + nt * 16 + lane15;
                long off = (long)row * ldc + col;
                float v = acc[mt][nt][i];
                if (task == 0) {
                    u16 h_ = f2bf(v);
                    sq1H[off] = h_;
                    sq1L[off] = f2bf(v - bf2f(h_));
                } else if (task == 1) {
                    E0q[off] = v;
                } else if (task == 2) {
                    E0o[off] = v;
                } else {
                    xW[off] = v + biasc[col];
                }
            }
}

__global__ __launch_bounds__(256) void gemm_head_k(
    int bid_off,
    const u16* __restrict__ enc1H, const u16* __restrict__ enc1L,
    const u16* __restrict__ wqTH,  const u16* __restrict__ wqTL,
    const u16* __restrict__ enc0H, const u16* __restrict__ enc0L,
    const u16* __restrict__ wqdTH, const u16* __restrict__ wqdTL,
    const u16* __restrict__ woCH,  const u16* __restrict__ woCL,
    const u16* __restrict__ xinH,  const u16* __restrict__ xinL,
    const u16* __restrict__ WihH,  const u16* __restrict__ WihL,
    u16* __restrict__ sq1H, u16* __restrict__ sq1L,
    float* __restrict__ E0q, float* __restrict__ E0o,
    float* __restrict__ xW, const float* __restrict__ biasc)
{
    __shared__ u16 sm[4 * 128 * 40];
    run_head_gemm(blockIdx.x + bid_off, sm,
                  enc1H, enc1L, wqTH, wqTL, enc0H, enc0L, wqdTH, wqdTL,
                  woCH, woCL, xinH, xinL, WihH, WihL,
                  sq1H, sq1L, E0q, E0o, xW, biasc);
}

// ---------------------------------------------------------------------------
// Logits GEMM: 256x128 tile, 512 threads (8 waves = 4m x 2n),
// global_load_lds staging + nontemporal C stores.
// ---------------------------------------------------------------------------
#define GLOAD_LDS16(gsrc, ldst) \
    __builtin_amdgcn_global_load_lds((const __attribute__((address_space(1))) u32*)(gsrc), \
                                     (__attribute__((address_space(3))) u32*)(ldst), 16, 0, 0)

__global__ __launch_bounds__(512) void gemm_lds_bias256(
    const u16* __restrict__ A, const u16* __restrict__ B,
    float* __restrict__ C, const float* __restrict__ bias, int ldc, int K)
{
    __shared__ u16 sA[256 * 32];
    __shared__ u16 sB[128 * 32];

    const int tid = threadIdx.x;
    const int lane = tid & 63, w = tid >> 6;
    const int wm = w >> 1, wn = w & 1;        // 4m x 2n wave grid
    const int lane15 = lane & 15, q8 = (lane >> 4) << 3;
    const int m0 = blockIdx.x * 256;          // m fast: consecutive bids share B
    const int n0 = blockIdx.y * 128;

    const int srow = lane >> 2, schunk = (lane & 3) * 8;

    f32x4 acc[4][4] = {};

    for (int k0 = 0; k0 < K; k0 += 32) {
        // A: 256 rows, 32 rows/wave (2 calls); B: 128 rows, 16 rows/wave (1 call)
#pragma unroll
        for (int c = 0; c < 2; ++c) {
            int base_r = w * 32 + c * 16;
            const u16* ga = A + (long)(m0 + base_r + srow) * 512 + k0 + schunk;
            GLOAD_LDS16(ga, &sA[base_r * 32]);
        }
        {
            int base_r = w * 16;
            const u16* gb = B + (long)(n0 + base_r + srow) * 512 + k0 + schunk;
            GLOAD_LDS16(gb, &sB[base_r * 32]);
        }
        __syncthreads();

        bf16x8 a[4], b[4];
#pragma unroll
        for (int i = 0; i < 4; ++i) {
            a[i] = *(const bf16x8*)&sA[(wm * 64 + i * 16 + lane15) * 32 + q8];
            b[i] = *(const bf16x8*)&sB[(wn * 64 + i * 16 + lane15) * 32 + q8];
        }
#pragma unroll
        for (int mt = 0; mt < 4; ++mt)
#pragma unroll
            for (int nt = 0; nt < 4; ++nt)
                acc[mt][nt] = __builtin_amdgcn_mfma_f32_16x16x32_bf16(a[mt], b[nt], acc[mt][nt], 0, 0, 0);
        __syncthreads();
    }

#pragma unroll
    for (int mt = 0; mt < 4; ++mt)
#pragma unroll
        for (int nt = 0; nt < 4; ++nt)
#pragma unroll
            for (int i = 0; i < 4; ++i) {
                int row = m0 + wm * 64 + mt * 16 + ((lane >> 4) << 2) + i;
                int col = n0 + wn * 64 + nt * 16 + lane15;
                __builtin_nontemporal_store(acc[mt][nt][i] + bias[col], &C[(long)row * ldc + col]);
            }
}

// ---------------------------------------------------------------------------
// Merged kernel: blocks 0-127 = doc loop; blocks 128-867 = sq1/xW GEMMs
// (fill CUs left idle by doc's barrier waits; always terminate -> no deadlock).
// ---------------------------------------------------------------------------
__global__ __launch_bounds__(256) void doc_plus_gemm(
    const float* __restrict__ enc0, const float* __restrict__ E0q,
    const float* __restrict__ E0o, const unsigned char* __restrict__ mask,
    const float* __restrict__ emb,
    const u16* __restrict__ WpH, const u16* __restrict__ WpL,
    const float* __restrict__ biasd, const float* __restrict__ wo_d,
    u32* __restrict__ dxP, u32* __restrict__ hP0, u32* __restrict__ hP1,
    u32* __restrict__ dcP, u32* __restrict__ dscP,
    float* __restrict__ dsent, float* __restrict__ out_last, u32* bar,
    const u16* __restrict__ enc1H, const u16* __restrict__ enc1L,
    const u16* __restrict__ wqTH,  const u16* __restrict__ wqTL,
    const u16* __restrict__ enc0H, const u16* __restrict__ enc0L,
    const u16* __restrict__ wqdTH, const u16* __restrict__ wqdTL,
    const u16* __restrict__ woCH,  const u16* __restrict__ woCL,
    const u16* __restrict__ xinH,  const u16* __restrict__ xinL,
    const u16* __restrict__ WihH,  const u16* __restrict__ WihL,
    u16* __restrict__ sq1H, u16* __restrict__ sq1L,
    float* __restrict__ xW, const float* __restrict__ biasc)
{
    __shared__ __attribute__((aligned(16))) char SM[75776];

    if (blockIdx.x >= 128) {
        int g = blockIdx.x - 128;
        int bid = (g < 100) ? g : g + 200;     // 0-99 sq1, 300-939 xW
        run_head_gemm(bid, (u16*)SM,
                      enc1H, enc1L, wqTH, wqTL, enc0H, enc0L, wqdTH, wqdTL,
                      woCH, woCL, xinH, xinL, WihH, WihL,
                      sq1H, sq1L, nullptr, nullptr, xW, biasc);
        return;
    }

    // ---- doc region ----
    u16* xhH = (u16*)SM;                         // [16][1032]
    u16* xhL = xhH + 16 * 1032;
    float* fb = (float*)(SM + 66048);
    float* red4 = fb;                            // [4][272]
    float* aux2 = fb + 1088;                     // [512]
    float* sc_s = fb + 1600;                     // [512]
    float* whoh_s = fb + 2112;                   // [32]
    float* ctxp = fb + 2144;                     // [8][32]
    float* rtmp = fb + 2400;                     // [8]

    const int blk = blockIdx.x, tid = threadIdx.x;
    const int w = tid >> 6, lane = tid & 63;
    const int b_ = blk >> 4, s = blk & 15;
    const int lane15 = lane & 15, q8 = (lane >> 4) << 3;
    u32* fF = bar;
    u32* fG = bar + 4096 + b_ * 512;
    u32 genF = 0, genG = 0;

    for (int q = tid; q < 8 * 1032; q += 256) { xhH[8 * 1032 + q] = 0; xhL[8 * 1032 + q] = 0; }

    {   // init: dh = dc = mean_j enc0[b,j,:], dx = emb[SOD]
        int dd = tid & 31, part = tid >> 5;
        const float* p0 = enc0 + ((long)b_ * 400 + part * 50) * 512 + s * 32 + dd;
        float sm = 0.f;
#pragma unroll 10
        for (int j = 0; j < 50; ++j) { sm += *p0; p0 += 512; }
        ctxp[part * 32 + dd] = sm;
        __syncthreads();
        if (tid < 32) {
            float m = 0.f;
#pragma unroll
            for (int p = 0; p < 8; ++p) m += ctxp[p * 32 + tid];
            m *= (1.f / 400.f);
            int e = s * 32 + tid;
            ast(&hP0[b_ * 512 + e], packsplit(m));
            ast(&dcP[b_ * 512 + e], __float_as_uint(m));
            ast(&dxP[b_ * 512 + e], packsplit(emb[1024 + e]));
        }
    }
    fbar<128>(fF, blk, ++genF);

    const int eb_b = tid & 7, eb_u4 = tid >> 3, eb_u = blk * 4 + eb_u4;
    float dcr = 0.f;
    if (tid < 32) dcr = __uint_as_float(ald(&dcP[eb_b * 512 + eb_u]));

    const u16* bh_base = WpH + ((long)blk * 16 + lane15) * 1024 + (w << 8) + q8;
    const u16* bl_base = WpL + ((long)blk * 16 + lane15) * 1024 + (w << 8) + q8;
    const u16* ah_base = xhH + lane15 * 1032 + (w << 8) + q8;
    const u16* al_base = xhL + lane15 * 1032 + (w << 8) + q8;

    for (int t = 0; t < 16; ++t) {
        u32* hinP = (t & 1) ? hP1 : hP0;
        u32* houtP = (t & 1) ? hP0 : hP1;

        // ---- A: stage packed x|h into LDS (2 batches of 16 coherent loads) ----
#pragma unroll
        for (int half = 0; half < 2; ++half) {
            u32 px[8], ph[8];
#pragma unroll
            for (int j = 0; j < 8; ++j) {
                int q = half * 2048 + j * 256 + tid;
                px[j] = ald(&dxP[q]);
                ph[j] = ald(&hinP[q]);
            }
#pragma unroll
            for (int j = 0; j < 8; ++j) {
                int q = half * 2048 + j * 256 + tid;
                int o = (q >> 9) * 1032 + (q & 511);
                xhH[o] = (u16)px[j];           xhL[o] = (u16)(px[j] >> 16);
                xhH[o + 512] = (u16)ph[j];     xhL[o + 512] = (u16)(ph[j] >> 16);
            }
        }
        __syncthreads();

        // 4-way K-split MFMA
        f32x4 acc = {};
#pragma unroll
        for (int k0 = 0; k0 < 256; k0 += 32) {
            bf16x8 aH = *(const bf16x8*)&ah_base[k0];
            bf16x8 aL = *(const bf16x8*)&al_base[k0];
            bf16x8 bH = *(const bf16x8*)&bh_base[k0];
            bf16x8 bL = *(const bf16x8*)&bl_base[k0];
            acc = __builtin_amdgcn_mfma_f32_16x16x32_bf16(aH, bH, acc, 0, 0, 0);
            acc = __builtin_amdgcn_mfma_f32_16x16x32_bf16(aH, bL, acc, 0, 0, 0);
            acc = __builtin_amdgcn_mfma_f32_16x16x32_bf16(aL, bH, acc, 0, 0, 0);
        }
#pragma unroll
        for (int i = 0; i < 4; ++i)
            red4[w * 272 + ((lane >> 4) * 4 + i) * 17 + lane15] = acc[i];
        __syncthreads();

        if (tid < 32) {
            float g4[4];
#pragma unroll
            for (int g = 0; g < 4; ++g)
                g4[g] = red4[0 * 272 + eb_b * 17 + eb_u4 * 4 + g] + red4[1 * 272 + eb_b * 17 + eb_u4 * 4 + g]
                      + red4[2 * 272 + eb_b * 17 + eb_u4 * 4 + g] + red4[3 * 272 + eb_b * 17 + eb_u4 * 4 + g];
            float gi = g4[0] + biasd[eb_u];
            float gf = g4[1] + biasd[512 + eb_u];
            float gg = g4[2] + biasd[1024 + eb_u];
            float go = g4[3] + biasd[1536 + eb_u];
            dcr = sigm(gf) * dcr + sigm(gi) * tanhf(gg);
            float hv = sigm(go) * tanhf(dcr);
            ast(&houtP[eb_b * 512 + eb_u], packsplit(hv));
        }
        fbar<128>(fF, blk, ++genF);

        // ---- B: scores (j-slice) + whoh (8 rows/wave) ----
        {
            u32 p0 = ald(&houtP[b_ * 512 + tid]);
            u32 p1 = ald(&houtP[b_ * 512 + 256 + tid]);
            aux2[tid] = bf2f((u16)p0) + bf2f((u16)(p0 >> 16));
            aux2[256 + tid] = bf2f((u16)p1) + bf2f((u16)(p1 >> 16));
            __syncthreads();
            for (int jj = w; jj < 25; jj += 4) {
                int j = s * 25 + jj;
                const float4* er = (const float4*)(E0q + ((long)b_ * 400 + j) * 512) + lane * 2;
                const float4* hv = (const float4*)aux2 + lane * 2;
                float sv = dot4(er[0], hv[0]) + dot4(er[1], hv[1]);
                sv = wave_sum(sv);
                if (lane == 0)
                    ast(&dscP[b_ * 400 + j], __float_as_uint(mask[b_ * 400 + j] ? -1e9f : sv));
            }
#pragma unroll
            for (int r = 0; r < 8; ++r) {
                int d = s * 32 + w * 8 + r;
                const float4* wr = (const float4*)(wo_d + (long)d * 1024 + 512) + lane * 2;
                const float4* hv = (const float4*)aux2 + lane * 2;
                float sv = dot4(wr[0], hv[0]) + dot4(wr[1], hv[1]);
                sv = wave_sum(sv);
                if (lane == 0) whoh_s[w * 8 + r] = sv;
            }
        }
        fbar<16>(fG, s, ++genG);

        // ---- C: softmax + ctx (d-slice) + out ----
        {
            float v0 = __uint_as_float(ald(&dscP[b_ * 400 + tid]));
            bool h1 = (tid + 256) < 400;
            float v1 = h1 ? __uint_as_float(ald(&dscP[b_ * 400 + tid + 256])) : -1e30f;
            float mx = wave_max(fmaxf(v0, v1));
            if (lane == 0) rtmp[w] = mx;
            __syncthreads();
            float M = fmaxf(fmaxf(rtmp[0], rtmp[1]), fmaxf(rtmp[2], rtmp[3]));
            float e0 = expf(v0 - M);
            float e1 = h1 ? expf(v1 - M) : 0.f;
            float sv = wave_sum(e0 + e1);
            if (lane == 0) rtmp[4 + w] = sv;
            __syncthreads();
            float inv = 1.f / (rtmp[4] + rtmp[5] + rtmp[6] + rtmp[7]);
            sc_s[tid] = e0 * inv;
            if (h1) sc_s[tid + 256] = e1 * inv;
            __syncthreads();
            int dd = tid & 31, part = tid >> 5;
            const float* eo = E0o + ((long)b_ * 400 + part * 50) * 512 + s * 32 + dd;
            float acc2 = 0.f;
#pragma unroll 10
            for (int j = 0; j < 50; ++j) { acc2 += sc_s[part * 50 + j] * (*eo); eo += 512; }
            ctxp[part * 32 + dd] = acc2;
            __syncthreads();
            if (tid < 32) {
                int d = s * 32 + tid;
                float o = whoh_s[tid];
#pragma unroll
                for (int p = 0; p < 8; ++p) o += ctxp[p * 32 + tid];
                float val = tanhf(o);
                ast(&dxP[b_ * 512 + d], packsplit(val));
                dsent[((b_ << 4) + t) * 512 + d] = val;
                if (t == 15) out_last[b_ * 512 + d] = val;
            }
        }
        fbar<128>(fF, blk, ++genF);
    }
}

// ---------------------------------------------------------------------------
// Word-level loop (unchanged from round 10).
// ---------------------------------------------------------------------------
__global__ __launch_bounds__(512) void word_mega(
    const float* __restrict__ sentS,
    u32* __restrict__ hAllP,
    u16* __restrict__ hAllH, u16* __restrict__ hAllL,
    const u16* __restrict__ WhhH, const u16* __restrict__ WhhL,
    const float* __restrict__ xW,
    u16* __restrict__ catB, u32* bar)
{
    __shared__ float red[8][4][256];
    const int tid = threadIdx.x, blk = blockIdx.x;
    const int b2t = blk >> 5;
    const int u0 = (blk & 31) << 4;
    u32* fG = bar + 8192 + b2t * 1024;
    u32 genG = 0;

    float wcr = 0.f;
    long cidx = 0;
    int my_b2 = 0, my_u = 0;
    if (tid < 256) {
        my_b2 = b2t * 16 + (tid >> 4);
        my_u = u0 + (tid & 15);
        cidx = (long)my_b2 * 512 + my_u;
        wcr = sentS[cidx];
        ast(&hAllP[cidx], packsplit(wcr));
    }
    fbar<32>(fG, blk & 31, ++genG);

    const int w = tid >> 6, lane = tid & 63;
    const int lane15 = lane & 15, q8 = (lane >> 4) << 3;
    const long arowE = (long)(b2t * 16 + lane15) * 512 + w * 64 + q8;
    long brow[4];
#pragma unroll
    for (int g = 0; g < 4; ++g)
        brow[g] = (long)(g * 512 + u0 + lane15) * 512 + w * 64 + q8;

    for (int t = 0; t < 40; ++t) {
        const u32* hP = hAllP + (long)t * 65536;

        u32 ph[16];
#pragma unroll
        for (int j = 0; j < 16; ++j)
            ph[j] = ald(&hP[arowE + (j >> 3) * 32 + (j & 7)]);

        float xw0 = 0.f, xw1 = 0.f, xw2 = 0.f, xw3 = 0.f;
        if (tid < 256) {
            const float* xr = xW + (long)t * 262144 + (long)my_b2 * 2048;
            xw0 = xr[my_u]; xw1 = xr[512 + my_u]; xw2 = xr[1024 + my_u]; xw3 = xr[1536 + my_u];
        }

        f32x4 acc[4] = {};
#pragma unroll
        for (int half = 0; half < 2; ++half) {
            int k0 = half * 32;
            bf16x8 aH, aL;
#pragma unroll
            for (int j = 0; j < 8; ++j) {
                u32 p = ph[half * 8 + j];
                aH[j] = (short)(p & 0xffffu);
                aL[j] = (short)(p >> 16);
            }
#pragma unroll
            for (int g = 0; g < 4; ++g) {
                bf16x8 bH = *(const bf16x8*)&WhhH[brow[g] + k0];
                bf16x8 bL = *(const bf16x8*)&WhhL[brow[g] + k0];
                acc[g] = __builtin_amdgcn_mfma_f32_16x16x32_bf16(aH, bH, acc[g], 0, 0, 0);
                acc[g] = __builtin_amdgcn_mfma_f32_16x16x32_bf16(aH, bL, acc[g], 0, 0, 0);
                acc[g] = __builtin_amdgcn_mfma_f32_16x16x32_bf16(aL, bH, acc[g], 0, 0, 0);
            }
        }
#pragma unroll
        for (int g = 0; g < 4; ++g)
#pragma unroll
            for (int i = 0; i < 4; ++i)
                red[w][g][((lane >> 4) * 4 + i) * 16 + lane15] = acc[g][i];
        __syncthreads();

        if (tid < 256) {
            float g4[4] = {0.f, 0.f, 0.f, 0.f};
#pragma unroll
            for (int ks = 0; ks < 8; ++ks)
#pragma unroll
                for (int g = 0; g < 4; ++g)
                    g4[g] += red[ks][g][tid];
            float gi = g4[0] + xw0;
            float gf = g4[1] + xw1;
            float gg = g4[2] + xw2;
            float go = g4[3] + xw3;
            wcr = sigm(gf) * wcr + sigm(gi) * tanhf(gg);
            float hv = sigm(go) * tanhf(wcr);
            u16 hh = f2bf(hv);
            u16 ll = f2bf(hv - bf2f(hh));
            long o = (long)(t + 1) * 65536 + cidx;
            ast(&hAllP[o], (u32)hh | ((u32)ll << 16));
            hAllH[o] = hh;
            hAllL[o] = ll;
            catB[((long)my_b2 * 40 + t) * 1024 + 512 + my_u] = hh;
        }
        fbar<32>(fG, blk & 31, ++genG);
    }
}

// ---------------------------------------------------------------------------
// All prep work in one region-dispatched kernel.
// ---------------------------------------------------------------------------
__device__ __forceinline__ void split1(const float* __restrict__ src,
                                       u16* __restrict__ H, u16* __restrict__ L, long i)
{
    float4 v = ((const float4*)src)[i];
    u16 h0 = f2bf(v.x), h1 = f2bf(v.y), h2 = f2bf(v.z), h3 = f2bf(v.w);
    ((us4*)H)[i] = {h0, h1, h2, h3};
    ((us4*)L)[i] = {f2bf(v.x - bf2f(h0)), f2bf(v.y - bf2f(h1)),
                    f2bf(v.z - bf2f(h2)), f2bf(v.w - bf2f(h3))};
}
__device__ __forceinline__ void wqT1(const float* __restrict__ wq,
                                     u16* __restrict__ H, u16* __restrict__ L, int idx)
{
    int e = idx >> 9, d = idx & 511;
    float v = wq[(long)d * 512 + e];
    u16 h = f2bf(v);
    H[idx] = h;
    L[idx] = f2bf(v - bf2f(h));
}

__global__ __launch_bounds__(256) void prep_all(
    const float* __restrict__ wih_w, const float* __restrict__ whh_w,
    const float* __restrict__ enc1, const float* __restrict__ enc0,
    const float* __restrict__ wq_w, const float* __restrict__ wq_d,
    const float* __restrict__ wo_w, const float* __restrict__ fcw,
    const int* __restrict__ toks, const float* __restrict__ emb,
    const float* __restrict__ spe,
    const float* __restrict__ bih_w, const float* __restrict__ bhh_w,
    const float* __restrict__ bih_d, const float* __restrict__ bhh_d,
    const float* __restrict__ wih_d, const float* __restrict__ whh_d,
    const float* __restrict__ wo_d,
    u16* __restrict__ WihH, u16* __restrict__ WihL,
    u16* __restrict__ WhhH, u16* __restrict__ WhhL,
    u16* __restrict__ enc1H, u16* __restrict__ enc1L,
    u16* __restrict__ enc0H, u16* __restrict__ enc0L,
    u16* __restrict__ wqTH, u16* __restrict__ wqTL,
    u16* __restrict__ wqdTH, u16* __restrict__ wqdTL,
    u16* __restrict__ woB, u16* __restrict__ fcwB, u16* __restrict__ enc1T,
    u16* __restrict__ xinH, u16* __restrict__ xinL,
    u16* __restrict__ woCH, u16* __restrict__ woCL,
    u16* __restrict__ WpH, u16* __restrict__ WpL,
    float* __restrict__ biasc, float* __restrict__ biasd,
    float* __restrict__ out_attn, u32* __restrict__ bar)
{
    int b = blockIdx.x;
    const int tid = threadIdx.x;

    if (b < 1024) { split1(wih_w, WihH, WihL, (long)b * 256 + tid); return; }
    b -= 1024;
    if (b < 1024) { split1(whh_w, WhhH, WhhL, (long)b * 256 + tid); return; }
    b -= 1024;
    if (b < 1600) { split1(enc1, enc1H, enc1L, (long)b * 256 + tid); return; }
    b -= 1600;
    if (b < 1600) { split1(enc0, enc0H, enc0L, (long)b * 256 + tid); return; }
    b -= 1600;
    if (b < 1024) { wqT1(wq_w, wqTH, wqTL, b * 256 + tid); return; }
    b -= 1024;
    if (b < 1024) { wqT1(wq_d, wqdTH, wqdTL, b * 256 + tid); return; }
    b -= 1024;
    if (b < 512) {
        long i = (long)b * 256 + tid;
        float4 v = ((const float4*)wo_w)[i];
        ((us4*)woB)[i] = {f2bf(v.x), f2bf(v.y), f2bf(v.z), f2bf(v.w)};
        return;
    }
    b -= 512;
    if (b < 16000) {
        long i = (long)b * 256 + tid;
        float4 v = ((const float4*)fcw)[i];
        ((us4*)fcwB)[i] = {f2bf(v.x), f2bf(v.y), f2bf(v.z), f2bf(v.w)};
        return;
    }
    b -= 16000;
    if (b < 6656) {
        long idx = (long)b * 256 + tid;
        int j = (int)(idx % 416);
        long be = idx / 416;
        int e = (int)(be % 512);
        int bb = (int)(be / 512);
        float v = (j < 400) ? enc1[((long)bb * 400 + j) * 512 + e] : 0.f;
        enc1T[idx] = f2bf(v);
        return;
    }
    b -= 6656;
    if (b < 1280) {
        int g = b * 256 + tid;
        int m = g >> 6, e0 = (g & 63) << 3;
        int t = m >> 7, b2 = m & 127;
        int ne = 0;
        for (int s = 0; s < 40; ++s) ne |= (toks[b2 * 40 + s] != 1);
        int pos = ne ? (2 + (b2 & 15)) : 1;
        const float* ep = emb + (long)toks[b2 * 40 + t] * 512 + e0;
        const float* sp = spe + (long)pos * 512 + e0;
        long o = (long)m * 512 + e0;
#pragma unroll
        for (int j = 0; j < 8; ++j) {
            float v = ep[j] + sp[j];
            u16 h = f2bf(v);
            xinH[o + j] = h;
            xinL[o + j] = f2bf(v - bf2f(h));
        }
        return;
    }
    b -= 1280;
    if (b < 1) {
        for (int i = tid; i < 2048; i += 256) {
            biasc[i] = bih_w[i] + bhh_w[i];
            biasd[i] = bih_d[i] + bhh_d[i];
        }
        return;
    }
    b -= 1;
    if (b < 200) {
        out_attn[b * 256 + tid] = 0.f;
        return;
    }
    b -= 200;
    if (b < 1024) {
        int i = b * 256 + tid;
        int d = i >> 9, e = i & 511;
        float v = wo_d[(long)d * 1024 + e];
        u16 h = f2bf(v);
        woCH[i] = h;
        woCL[i] = f2bf(v - bf2f(h));
        return;
    }
    b -= 1024;
    if (b < 1024) {
        long gidx = (long)b * 256 + tid;
        int r = (int)(gidx >> 7);
        int k8 = ((int)gidx & 127) * 8;
        int u = r >> 2, g = r & 3;
        long orow = (long)(g * 512 + u);
#pragma unroll
        for (int j = 0; j < 8; ++j) {
            int k = k8 + j;
            float v = (k < 512) ? wih_d[orow * 512 + k] : whh_d[orow * 512 + k - 512];
            u16 h = f2bf(v);
            WpH[(long)r * 1024 + k] = h;
            WpL[(long)r * 1024 + k] = f2bf(v - bf2f(h));
        }
        return;
    }
    b -= 1024;
    // zero the flag-barrier region: 64 blocks x 256 = 16384 u32
    bar[b * 256 + tid] = 0;
}

__global__ __launch_bounds__(256) void word_softmax(
    const float* __restrict__ sc, const unsigned char* __restrict__ mask,
    float* __restrict__ pout, u16* __restrict__ pbf)
{
    const int r = blockIdx.x, tid = threadIdx.x;
    const int b = r / 640;
    const int wv = tid >> 6, lane = tid & 63;
    __shared__ float red[4];
    const int j1 = tid + 256;
    float v0 = sc[(long)r * 512 + tid];
    if (mask[b * 400 + tid]) v0 = -1e9f;
    float v1 = -1e30f;
    if (j1 < 400) {
        v1 = sc[(long)r * 512 + j1];
        if (mask[b * 400 + j1]) v1 = -1e9f;
    }
    float mv = wave_max(fmaxf(v0, v1));
    if (lane == 0) red[wv] = mv;
    __syncthreads();
    if (tid == 0) red[0] = fmaxf(fmaxf(red[0], red[1]), fmaxf(red[2], red[3]));
    __syncthreads();
    const float M = red[0];
    float e0 = expf(v0 - M);
    float e1 = (j1 < 400) ? expf(v1 - M) : 0.f;
    __syncthreads();
    float sv = wave_sum(e0 + e1);
    if (lane == 0) red[wv] = sv;
    __syncthreads();
    if (tid == 0) red[0] = red[0] + red[1] + red[2] + red[3];
    __syncthreads();
    const float inv = 1.f / red[0];
    float p0 = e0 * inv;
    __builtin_nontemporal_store(p0, &pout[(long)r * 400 + tid]);
    pbf[(long)r * 416 + tid] = f2bf(p0);
    if (j1 < 400) {
        float p1 = e1 * inv;
        __builtin_nontemporal_store(p1, &pout[(long)r * 400 + j1]);
        pbf[(long)r * 416 + j1] = f2bf(p1);
    } else if (j1 < 416) {
        pbf[(long)r * 416 + j1] = 0;
    }
}

// ---------------------------------------------------------------------------
extern "C" void kernel_launch(void* const* d_in, const int* in_sizes, int n_in,
                              void* d_out, int out_size, void* d_ws, size_t ws_size,
                              hipStream_t stream)
{
    (void)in_sizes; (void)n_in; (void)out_size; (void)ws_size;

    const int*   toks  = (const int*)  d_in[0];
    const float* enc0  = (const float*)d_in[1];
    const float* enc1  = (const float*)d_in[2];
    const unsigned char* mask = (const unsigned char*)d_in[3];
    const float* emb   = (const float*)d_in[4];
    const float* spe   = (const float*)d_in[5];
    const float* wih_d = (const float*)d_in[6];
    const float* whh_d = (const float*)d_in[7];
    const float* bih_d = (const float*)d_in[8];
    const float* bhh_d = (const float*)d_in[9];
    const float* wq_d  = (const float*)d_in[10];
    const float* wo_d  = (const float*)d_in[11];
    const float* wih_w = (const float*)d_in[12];
    const float* whh_w = (const float*)d_in[13];
    const float* bih_w = (const float*)d_in[14];
    const float* bhh_w = (const float*)d_in[15];
    const float* wq_w  = (const float*)d_in[16];
    const float* wo_w  = (const float*)d_in[17];
    const float* fcw   = (const float*)d_in[18];
    const float* fcb   = (const float*)d_in[19];

    float* out_dec  = (float*)d_out;                  // [8,640,32000]
    float* out_attn = out_dec + 163840000L;           // [8,16,400] zeros
    float* out_watt = out_attn + 51200;               // [128,40,400]
    float* out_last = out_watt + 2048000;             // [8,512]

    char* wsp = (char*)d_ws;
    auto alloc = [&](size_t bytes) -> void* {
        void* p = wsp;
        wsp += (bytes + 255) & ~(size_t)255;
        return p;
    };

    float* xW    = (float*)alloc(40L * 128 * 2048 * 4);
    u32* hAllP   = (u32*)alloc(41L * 128 * 512 * 4);
    u16* hAllH   = (u16*)alloc(41L * 128 * 512 * 2);
    u16* hAllL   = (u16*)alloc(41L * 128 * 512 * 2);
    u16* xinH    = (u16*)alloc(5120L * 512 * 2);
    u16* xinL    = (u16*)alloc(5120L * 512 * 2);
    u16* WihH    = (u16*)alloc(2048L * 512 * 2);
    u16* WihL    = (u16*)alloc(2048L * 512 * 2);
    u16* WhhH    = (u16*)alloc(2048L * 512 * 2);
    u16* WhhL    = (u16*)alloc(2048L * 512 * 2);
    u16* wqTH    = (u16*)alloc(512L * 512 * 2);
    u16* wqTL    = (u16*)alloc(512L * 512 * 2);
    u16* wqdTH   = (u16*)alloc(512L * 512 * 2);
    u16* wqdTL   = (u16*)alloc(512L * 512 * 2);
    u16* enc1H   = (u16*)alloc(3200L * 512 * 2);
    u16* enc1L   = (u16*)alloc(3200L * 512 * 2);
    u16* enc0H   = (u16*)alloc(3200L * 512 * 2);
    u16* enc0L   = (u16*)alloc(3200L * 512 * 2);
    u16* sq1H    = (u16*)alloc(3328L * 512 * 2);
    u16* sq1L    = (u16*)alloc(3328L * 512 * 2);
    float* E0q   = (float*)alloc(3200L * 512 * 4);
    float* E0o   = (float*)alloc(3200L * 512 * 4);
    u16* woCH    = (u16*)alloc(512L * 512 * 2);
    u16* woCL    = (u16*)alloc(512L * 512 * 2);
    u16* WpH     = (u16*)alloc(2048L * 1024 * 2);
    u16* WpL     = (u16*)alloc(2048L * 1024 * 2);
    float* wsS   = (float*)alloc(5120L * 512 * 4);
    u16* Pbf     = (u16*)alloc(5120L * 416 * 2);
    u16* enc1T   = (u16*)alloc(8L * 512 * 416 * 2);
    u16* catB    = (u16*)alloc(5120L * 1024 * 2);
    u16* woB     = (u16*)alloc(512L * 1024 * 2);
    u16* Alog    = (u16*)alloc(5120L * 512 * 2);
    u16* fcwB    = (u16*)alloc(32000L * 512 * 2);
    float* biasc = (float*)alloc(2048 * 4);
    float* biasd = (float*)alloc(2048 * 4);
    u32* dxP     = (u32*)alloc(4096 * 4);
    u32* hP0     = (u32*)alloc(4096 * 4);
    u32* hP1     = (u32*)alloc(4096 * 4);
    u32* dcP     = (u32*)alloc(4096 * 4);
    u32* dscP    = (u32*)alloc(3200 * 4);
    float* dsent = (float*)alloc(128L * 512 * 4);
    u32* bar     = (u32*)alloc(16384 * 4);

    // ---- 1: all prep (also zeroes out_attn and all flag lines) ----
    prep_all<<<dim3(34057), 256, 0, stream>>>(
        wih_w, whh_w, enc1, enc0, wq_w, wq_d, wo_w, fcw, toks, emb, spe,
        bih_w, bhh_w, bih_d, bhh_d, wih_d, whh_d, wo_d,
        WihH, WihL, WhhH, WhhL, enc1H, enc1L, enc0H, enc0L,
        wqTH, wqTL, wqdTH, wqdTL, woB, fcwB, enc1T, xinH, xinL,
        woCH, woCL, WpH, WpL, biasc, biasd, out_attn, bar);

    // ---- 2: E0q + E0o head GEMMs (needed by doc) ----
    gemm_head_k<<<dim3(200), 256, 0, stream>>>(
        100,
        enc1H, enc1L, wqTH, wqTL, enc0H, enc0L, wqdTH, wqdTL,
        woCH, woCL, xinH, xinL, WihH, WihL,
        sq1H, sq1L, E0q, E0o, xW, biasc);

    // ---- 3: doc loop (blocks 0-127) + sq1/xW GEMMs (blocks 128-867) ----
    doc_plus_gemm<<<dim3(868), 256, 0, stream>>>(
        enc0, E0q, E0o, mask, emb, WpH, WpL, biasd, wo_d,
        dxP, hP0, hP1, dcP, dscP, dsent, out_last, bar,
        enc1H, enc1L, wqTH, wqTL, enc0H, enc0L, wqdTH, wqdTL,
        woCH, woCL, xinH, xinL, WihH, WihL,
        sq1H, sq1L, xW, biasc);

    // ---- 4: word-level LSTM recurrence ----
    word_mega<<<dim3(256), 512, 0, stream>>>(
        dsent, hAllP, hAllH, hAllL, WhhH, WhhL, xW, catB, bar);

    // ---- 5: batched word attention scores ----
    gemm_bt<true, 1, 0><<<dim3(4, 5, 8), 256, 0, stream>>>(
        hAllH, hAllL, 0, 0, sq1H, sq1L, 512, 204800L,
        wsS, nullptr, nullptr, 512, 327680L, nullptr, 512);

    // ---- 6: softmax -> out_watt (nt) + Pbf ----
    word_softmax<<<dim3(5120), 256, 0, stream>>>(wsS, mask, out_watt, Pbf);

    // ---- 7: ctx = P @ enc1 -> catB[:, 0:512] ----
    gemm_bt<false, 0, 4><<<dim3(4, 5, 8), 256, 0, stream>>>(
        Pbf, nullptr, 416, 266240L, enc1T, nullptr, 416, 212992L,
        nullptr, catB, nullptr, 1024, 655360L, nullptr, 416);

    // ---- 8: out = tanh(cat @ wo^T) ----
    gemm_bt<false, 0, 3><<<dim3(4, 40, 1), 256, 0, stream>>>(
        catB, nullptr, 1024, 0, woB, nullptr, 1024, 0,
        nullptr, Alog, nullptr, 512, 0, nullptr, 1024);

    // ---- 9: logits via 256x128 global_load_lds GEMM + nt C stores ----
    gemm_lds_bias256<<<dim3(20, 250, 1), 512, 0, stream>>>(
        Alog, fcwB, out_dec, fcb, 32000, 512);
}